// Round 2
// baseline (371.255 us; speedup 1.0000x reference)
//
#include <hip/hip_runtime.h>

#define N 4096            // row length (elements)
#define NEG_BIG -9999999.9f

// Two waves (128 lanes) per row; 32 elements per lane, all in VGPRs.
// tau via Newton on f(t) = sum(relu(z - rmax + t)) - 1; converges to the
// reference's sorted-support formula exactly, early-exits at the fixed point.
__global__ __launch_bounds__(128, 6)
void sparsemax_kernel(const float* __restrict__ x,
                      const float* __restrict__ m,
                      float* __restrict__ out) {
    const int lane = threadIdx.x & 63;
    const int wave = threadIdx.x >> 6;           // 0 or 1
    const int row  = blockIdx.x;

    // Each wave owns half the row: 2048 elems = 512 float4; lane-strided.
    const size_t base = (size_t)row * (N / 4) + (size_t)wave * (N / 8);
    const float4* __restrict__ xr = (const float4*)x + base;
    const float4* __restrict__ mr = (const float4*)m + base;
    float4* __restrict__ outr     = (float4*)out + base;

    // Load half-row: z = (mask ? x : NEG_BIG) * 2   (/(1-TEMP), TEMP=0.5)
    float z[32];
    float rmax = -3.0e38f;
#pragma unroll
    for (int j = 0; j < 8; ++j) {
        float4 xv = xr[j * 64 + lane];
        float4 mv = mr[j * 64 + lane];
        float z0 = (mv.x != 0.0f ? xv.x : NEG_BIG) * 2.0f;
        float z1 = (mv.y != 0.0f ? xv.y : NEG_BIG) * 2.0f;
        float z2 = (mv.z != 0.0f ? xv.z : NEG_BIG) * 2.0f;
        float z3 = (mv.w != 0.0f ? xv.w : NEG_BIG) * 2.0f;
        z[4 * j + 0] = z0;
        z[4 * j + 1] = z1;
        z[4 * j + 2] = z2;
        z[4 * j + 3] = z3;
        rmax = fmaxf(rmax, fmaxf(fmaxf(z0, z1), fmaxf(z2, z3)));
    }

    // Wave-wide max butterfly, then cross-wave combine via LDS.
#pragma unroll
    for (int k = 32; k >= 1; k >>= 1)
        rmax = fmaxf(rmax, __shfl_xor(rmax, k, 64));

    __shared__ float smax[2];
    __shared__ float2 sparts[2][2];              // [parity][wave] = {s, c}
    if (lane == 0) smax[wave] = rmax;
    __syncthreads();
    rmax = fmaxf(smax[0], smax[1]);

    // Newton on u = t - rmax, t0 = 1  (f(t0) >= 1 guarantees support >= 1,
    // c >= 1, and monotone convergence from above).
    float u = 1.0f - rmax;
    int parity = 0;
    for (int it = 0; it < 24; ++it) {
        float s = 0.0f, c = 0.0f;
#pragma unroll
        for (int i = 0; i < 32; ++i) {
            float v = z[i] + u;
            s += fmaxf(v, 0.0f);
            c += (v > 0.0f) ? 1.0f : 0.0f;
        }
#pragma unroll
        for (int k = 32; k >= 1; k >>= 1) {
            s += __shfl_xor(s, k, 64);
            c += __shfl_xor(c, k, 64);
        }
        if (lane == 0) sparts[parity][wave] = make_float2(s, c);
        __syncthreads();
        // Both waves compute identical totals -> u_new identical -> the
        // early-exit branch below is block-uniform (free).
        float2 p0 = sparts[parity][0];
        float2 p1 = sparts[parity][1];
        float S = p0.x + p1.x;
        float C = p0.y + p1.y;
        float un = u - (S - 1.0f) / C;
        parity ^= 1;
        if (un == u) break;                       // exact fixed point reached
        u = un;
        // Double-buffered sparts: next write goes to the other parity slot,
        // so no second barrier is needed (writer of slot p at iter i+2 is
        // gated behind the barrier of iter i+1, after all reads of p).
    }

    // All-masked row: reference multiplies by mask -> exact zeros.
    const float live = (rmax == NEG_BIG * 2.0f) ? 0.0f : 1.0f;

#pragma unroll
    for (int j = 0; j < 8; ++j) {
        float4 o;
        o.x = fmaxf(z[4 * j + 0] + u, 0.0f) * live;
        o.y = fmaxf(z[4 * j + 1] + u, 0.0f) * live;
        o.z = fmaxf(z[4 * j + 2] + u, 0.0f) * live;
        o.w = fmaxf(z[4 * j + 3] + u, 0.0f) * live;
        outr[j * 64 + lane] = o;
    }
}

extern "C" void kernel_launch(void* const* d_in, const int* in_sizes, int n_in,
                              void* d_out, int out_size, void* d_ws, size_t ws_size,
                              hipStream_t stream) {
    const float* x = (const float*)d_in[0];
    const float* m = (const float*)d_in[1];
    float* out = (float*)d_out;
    const int rows = in_sizes[0] / N;            // 8192
    sparsemax_kernel<<<rows, 128, 0, stream>>>(x, m, out);
}

// Round 3
// 320.156 us; speedup vs baseline: 1.1596x; 1.1596x over previous
//
#include <hip/hip_runtime.h>

#define N 4096            // row length
#define NEG_BIG -9999999.9f
#define CAP 512           // candidate buffer capacity per row

// One wave per row, 4 rows per 256-thread block. z[64] stays in VGPRs.
// Support of sparsemax is within {z > rmax-1}; for Gaussian data that's ~5
// of 4096 elements, so Newton runs on a tiny LDS-broadcast candidate set
// with no per-iteration cross-lane reductions.
__global__ __launch_bounds__(256, 4)
void sparsemax_kernel(const float* __restrict__ x,
                      const float* __restrict__ m,
                      float* __restrict__ out,
                      int rows) {
    const int lane = threadIdx.x & 63;
    const int wave = threadIdx.x >> 6;
    const int row  = blockIdx.x * 4 + wave;
    if (row >= rows) return;

    __shared__ float cand[4][CAP];   // w = z - rmax of candidates
    __shared__ int   cnt[4];
    if (threadIdx.x < 4) cnt[threadIdx.x] = 0;

    const float4* __restrict__ xr = (const float4*)x + (size_t)row * (N / 4);
    const float4* __restrict__ mr = (const float4*)m + (size_t)row * (N / 4);
    float4* __restrict__ outr     = (float4*)out + (size_t)row * (N / 4);

    // Load row: z = (mask ? x : NEG_BIG) * 2   (/(1-TEMP), TEMP=0.5)
    float z[64];
    float rmax = -3.0e38f;
#pragma unroll
    for (int j = 0; j < 16; ++j) {
        float4 xv = xr[j * 64 + lane];
        float4 mv = mr[j * 64 + lane];
        float z0 = (mv.x != 0.0f ? xv.x : NEG_BIG) * 2.0f;
        float z1 = (mv.y != 0.0f ? xv.y : NEG_BIG) * 2.0f;
        float z2 = (mv.z != 0.0f ? xv.z : NEG_BIG) * 2.0f;
        float z3 = (mv.w != 0.0f ? xv.w : NEG_BIG) * 2.0f;
        z[4 * j + 0] = z0;
        z[4 * j + 1] = z1;
        z[4 * j + 2] = z2;
        z[4 * j + 3] = z3;
        rmax = fmaxf(rmax, fmaxf(fmaxf(z0, z1), fmaxf(z2, z3)));
    }

    // Wave-wide max butterfly
#pragma unroll
    for (int k = 32; k >= 1; k >>= 1)
        rmax = fmaxf(rmax, __shfl_xor(rmax, k, 64));

    __syncthreads();   // cnt init visible (also orders nothing else; cheap)

    // Append candidates w = z - rmax with w > -1 to this wave's LDS buffer.
    const float thr0 = rmax - 1.0f;
#pragma unroll
    for (int i = 0; i < 64; ++i) {
        if (z[i] > thr0) {
            int idx = atomicAdd(&cnt[wave], 1);
            if (idx < CAP) cand[wave][idx] = z[i] - rmax;
        }
    }
    __syncthreads();   // appends visible to all lanes of the wave

    const int K = cnt[wave];
    float u;           // solves sum_i max(w_i - u, 0) = 1,  u in [-1, 0)
    if (K <= CAP) {
        // Tiny-set Newton, identical on every lane (LDS broadcast reads).
        u = -1.0f;
        for (int it = 0; it < 32; ++it) {
            float s = 0.0f, c = 0.0f;
            for (int j = 0; j < K; ++j) {
                float v = cand[wave][j] - u;
                if (v > 0.0f) { s += v; c += 1.0f; }
            }
            float un = u + (s - 1.0f) / c;   // monotone non-decreasing
            if (!(un > u)) break;            // exact fixed point (uniform)
            u = un;
        }
    } else {
        // Fallback: butterfly Newton over the full row (any input, incl.
        // all-masked rows where every element ties at w = 0).
        u = -1.0f;
        for (int it = 0; it < 32; ++it) {
            float s = 0.0f, c = 0.0f;
#pragma unroll
            for (int i = 0; i < 64; ++i) {
                float v = (z[i] - rmax) - u;
                if (v > 0.0f) { s += v; c += 1.0f; }
            }
#pragma unroll
            for (int k = 32; k >= 1; k >>= 1) {
                s += __shfl_xor(s, k, 64);
                c += __shfl_xor(c, k, 64);
            }
            float un = u + (s - 1.0f) / c;
            if (!(un > u)) break;            // wave-uniform
            u = un;
        }
    }

    // All-masked row: reference multiplies by mask -> exact zeros.
    const float live = (rmax == NEG_BIG * 2.0f) ? 0.0f : 1.0f;
    const float thr  = rmax + u;             // = tau

#pragma unroll
    for (int j = 0; j < 16; ++j) {
        float4 o;
        o.x = fmaxf(z[4 * j + 0] - thr, 0.0f) * live;
        o.y = fmaxf(z[4 * j + 1] - thr, 0.0f) * live;
        o.z = fmaxf(z[4 * j + 2] - thr, 0.0f) * live;
        o.w = fmaxf(z[4 * j + 3] - thr, 0.0f) * live;
        outr[j * 64 + lane] = o;
    }
}

extern "C" void kernel_launch(void* const* d_in, const int* in_sizes, int n_in,
                              void* d_out, int out_size, void* d_ws, size_t ws_size,
                              hipStream_t stream) {
    const float* x = (const float*)d_in[0];
    const float* m = (const float*)d_in[1];
    float* out = (float*)d_out;
    const int rows = in_sizes[0] / N;           // 8192
    const int blocks = (rows + 3) / 4;          // 1 wave per row
    sparsemax_kernel<<<blocks, 256, 0, stream>>>(x, m, out, rows);
}

// Round 4
// 310.027 us; speedup vs baseline: 1.1975x; 1.0327x over previous
//
#include <hip/hip_runtime.h>

#define N 4096            // row length
#define NEG_BIG -9999999.9f
#define CAP 256           // candidate buffer capacity per row

// Two waves (128 threads) per row, one row per block; 32 elems/lane in VGPRs
// (~50 VGPRs -> 8 waves/SIMD tier, no spill). tau via Newton on the tiny
// candidate set {z > rmax-1} (provably contains the sparsemax support);
// every lane runs it redundantly from LDS broadcasts -> no per-iteration
// cross-lane reductions. Overflow (e.g. all-masked row) -> butterfly path.
// NOTE: no min-waves launch-bound -- (128,6)/(256,4) made the allocator
// under-allocate and spill the live z array (rounds 2-3).
__global__ __launch_bounds__(128)
void sparsemax_kernel(const float* __restrict__ x,
                      const float* __restrict__ m,
                      float* __restrict__ out) {
    const int lane = threadIdx.x & 63;
    const int wave = threadIdx.x >> 6;           // 0 or 1
    const int row  = blockIdx.x;

    __shared__ float  smax[2];
    __shared__ float2 sparts[2][2];              // [parity][wave] fallback partials
    __shared__ float  cand[CAP];                 // w = z - rmax of candidates
    __shared__ int    cnt;
    if (threadIdx.x == 0) cnt = 0;

    // Each wave owns half the row: 2048 elems = 512 float4, lane-strided.
    const size_t base = (size_t)row * (N / 4) + (size_t)wave * (N / 8);
    const float4* __restrict__ xr = (const float4*)x + base;
    const float4* __restrict__ mr = (const float4*)m + base;
    float4* __restrict__ outr     = (float4*)out + base;

    // Load half-row: z = (mask ? x : NEG_BIG) * 2   (/(1-TEMP), TEMP=0.5)
    float z[32];
    float rmax = -3.0e38f;
#pragma unroll
    for (int j = 0; j < 8; ++j) {
        float4 xv = xr[j * 64 + lane];
        float4 mv = mr[j * 64 + lane];
        float z0 = (mv.x != 0.0f ? xv.x : NEG_BIG) * 2.0f;
        float z1 = (mv.y != 0.0f ? xv.y : NEG_BIG) * 2.0f;
        float z2 = (mv.z != 0.0f ? xv.z : NEG_BIG) * 2.0f;
        float z3 = (mv.w != 0.0f ? xv.w : NEG_BIG) * 2.0f;
        z[4 * j + 0] = z0;
        z[4 * j + 1] = z1;
        z[4 * j + 2] = z2;
        z[4 * j + 3] = z3;
        rmax = fmaxf(rmax, fmaxf(fmaxf(z0, z1), fmaxf(z2, z3)));
    }

    // Wave-wide max butterfly, then cross-wave combine.
#pragma unroll
    for (int k = 32; k >= 1; k >>= 1)
        rmax = fmaxf(rmax, __shfl_xor(rmax, k, 64));
    if (lane == 0) smax[wave] = rmax;
    __syncthreads();                              // smax + cnt=0 visible
    rmax = fmaxf(smax[0], smax[1]);

    // Append candidates w = z - rmax with w > -1 (support must lie here,
    // since sum_support(z - tau) = 1 implies tau >= rmax - 1).
    const float thr0 = rmax - 1.0f;
#pragma unroll
    for (int i = 0; i < 32; ++i) {
        if (z[i] > thr0) {
            int idx = atomicAdd(&cnt, 1);
            if (idx < CAP) cand[idx] = z[i] - rmax;
        }
    }
    __syncthreads();                              // appends visible

    const int K = cnt;                            // block-uniform
    float u = -1.0f;                              // solve sum max(w-u,0)=1
    if (K <= CAP) {
        // Tiny-set Newton, identical on every lane (LDS broadcasts).
        for (int it = 0; it < 32; ++it) {
            float s = 0.0f, c = 0.0f;
            for (int j = 0; j < K; ++j) {
                float v = cand[j] - u;
                if (v > 0.0f) { s += v; c += 1.0f; }
            }
            float un = u + (s - 1.0f) / c;        // monotone non-decreasing
            if (!(un > u)) break;                 // exact fixed point
            u = un;
        }
    } else {
        // Fallback over the full row (e.g. all-masked: all w == 0).
        // K is block-uniform -> both waves take this branch; u sequence is
        // identical on both waves -> the break is block-uniform.
        int parity = 0;
        for (int it = 0; it < 32; ++it) {
            float s = 0.0f, c = 0.0f;
#pragma unroll
            for (int i = 0; i < 32; ++i) {
                float v = (z[i] - rmax) - u;
                if (v > 0.0f) { s += v; c += 1.0f; }
            }
#pragma unroll
            for (int k = 32; k >= 1; k >>= 1) {
                s += __shfl_xor(s, k, 64);
                c += __shfl_xor(c, k, 64);
            }
            if (lane == 0) sparts[parity][wave] = make_float2(s, c);
            __syncthreads();
            float2 p0 = sparts[parity][0];
            float2 p1 = sparts[parity][1];
            float S = p0.x + p1.x;
            float C = p0.y + p1.y;
            float un = u + (S - 1.0f) / C;
            parity ^= 1;                          // double-buffer: no 2nd barrier
            if (!(un > u)) break;
            u = un;
        }
    }

    // All-masked row: reference multiplies by mask -> exact zeros.
    const float live = (rmax == NEG_BIG * 2.0f) ? 0.0f : 1.0f;
    const float thr  = rmax + u;                  // = tau

#pragma unroll
    for (int j = 0; j < 8; ++j) {
        float4 o;
        o.x = fmaxf(z[4 * j + 0] - thr, 0.0f) * live;
        o.y = fmaxf(z[4 * j + 1] - thr, 0.0f) * live;
        o.z = fmaxf(z[4 * j + 2] - thr, 0.0f) * live;
        o.w = fmaxf(z[4 * j + 3] - thr, 0.0f) * live;
        outr[j * 64 + lane] = o;
    }
}

extern "C" void kernel_launch(void* const* d_in, const int* in_sizes, int n_in,
                              void* d_out, int out_size, void* d_ws, size_t ws_size,
                              hipStream_t stream) {
    const float* x = (const float*)d_in[0];
    const float* m = (const float*)d_in[1];
    float* out = (float*)d_out;
    const int rows = in_sizes[0] / N;             // 8192
    sparsemax_kernel<<<rows, 128, 0, stream>>>(x, m, out);
}